// Round 18
// baseline (59.714 us; speedup 1.0000x reference)
//
#include <hip/hip_runtime.h>

typedef __attribute__((ext_vector_type(8))) short short8;
typedef __attribute__((ext_vector_type(4))) float f32x4;
typedef __attribute__((ext_vector_type(16))) float f32x16;
typedef unsigned short ushort_t;

#define B_ 4
#define N_ 4096
#define E_ 256
#define D_ 64
#define S2LOG 0.1803368801111204f   // (1/sqrt(64)) * log2(e), folded into K' at proj
#define BIGNEG (-1e30f)
#define ROWPAT(r) ((((r)&3)) + 8*((r)>>2))
// vT key-position permutation: swap bits 2<->3 (involution)
#define KSWAP(n) (((n) & ~12) | (((n) & 4) << 1) | (((n) & 8) >> 1))

static __device__ __forceinline__ unsigned short f2bf(float f) {
  union { float f; unsigned int u; } v; v.f = f;
  return (unsigned short)((v.u + 0x7fffu + ((v.u >> 16) & 1u)) >> 16);  // RNE
}
static __device__ __forceinline__ float exp2_fast(float x) {
  float r; asm("v_exp_f32 %0, %1" : "=v"(r) : "v"(x)); return r;
}
static __device__ __forceinline__ unsigned cvt_pk_bf16(float lo, float hi) {
  unsigned r; asm("v_cvt_pk_bf16_f32 %0, %1, %2" : "=v"(r) : "v"(lo), "v"(hi));
  return r;
}

// ---------------------------------------------------------------------------
// Projection. p=0: q [B*N][64] (+ mask->bias f32); p=1: k' = S2LOG*k [B*N][64];
// p=2: vT [B][64][N] key-bit2<->3-swapped, PLUS fused vmean partials
// (16-lane shfl reduce over the block's 64 keys -> 1 atomicAdd per (d,r);
// uses pre-bf16-rounding f32 accs -> closer to the reference's f32 mean).
// ---------------------------------------------------------------------------
__global__ __launch_bounds__(256) void proj_kernel(
    const float* __restrict__ Qv, const float* __restrict__ Kv,
    const float* __restrict__ Vv, const float* __restrict__ Wq,
    const float* __restrict__ Wk, const float* __restrict__ Wv,
    const int* __restrict__ mask,
    unsigned short* __restrict__ qo, unsigned short* __restrict__ ko,
    unsigned short* __restrict__ vto, float* __restrict__ biasf,
    float* __restrict__ vmean)
{
  const int p  = blockIdx.y;
  const int rb = blockIdx.x;
  const int t  = threadIdx.x;

  __align__(16) __shared__ unsigned short Xl[64 * 264];
  __align__(16) __shared__ unsigned short Wl[64 * 264];

  const float* xsrc = (p == 0 ? Qv : (p == 1 ? Kv : Vv)) + (size_t)rb * 64 * E_;
  const float* wsrc = (p == 0 ? Wq : (p == 1 ? Wk : Wv));

  if (p == 0 && t < 64) biasf[rb * 64 + t] = mask[rb * 64 + t] ? 0.f : BIGNEG;

  #pragma unroll
  for (int it = 0; it < 8; ++it) {
    int idx = it * 2048 + t * 8;
    int row = idx >> 8, col = idx & 255;
    float4 a0 = *(const float4*)(xsrc + idx);
    float4 a1 = *(const float4*)(xsrc + idx + 4);
    uint4 wx;
    wx.x = (unsigned)f2bf(a0.x) | ((unsigned)f2bf(a0.y) << 16);
    wx.y = (unsigned)f2bf(a0.z) | ((unsigned)f2bf(a0.w) << 16);
    wx.z = (unsigned)f2bf(a1.x) | ((unsigned)f2bf(a1.y) << 16);
    wx.w = (unsigned)f2bf(a1.z) | ((unsigned)f2bf(a1.w) << 16);
    *(uint4*)&Xl[row * 264 + col] = wx;
    float4 b0 = *(const float4*)(wsrc + idx);
    float4 b1 = *(const float4*)(wsrc + idx + 4);
    uint4 ww;
    ww.x = (unsigned)f2bf(b0.x) | ((unsigned)f2bf(b0.y) << 16);
    ww.y = (unsigned)f2bf(b0.z) | ((unsigned)f2bf(b0.w) << 16);
    ww.z = (unsigned)f2bf(b1.x) | ((unsigned)f2bf(b1.y) << 16);
    ww.w = (unsigned)f2bf(b1.z) | ((unsigned)f2bf(b1.w) << 16);
    *(uint4*)&Wl[row * 264 + col] = ww;
  }
  __syncthreads();

  const int wave = t >> 6, lane = t & 63, g = lane >> 4, lq = lane & 15;
  const unsigned short* TA = (p == 2) ? Wl : Xl;
  const unsigned short* TB = (p == 2) ? Xl : Wl;

  f32x4 acc0 = {0.f,0.f,0.f,0.f}, acc1 = acc0, acc2 = acc0, acc3 = acc0;
  #pragma unroll
  for (int kc = 0; kc < 8; ++kc) {
    short8 af = *(const short8*)&TA[(wave * 16 + lq) * 264 + kc * 32 + g * 8];
    short8 b0 = *(const short8*)&TB[(0 * 16 + lq) * 264 + kc * 32 + g * 8];
    acc0 = __builtin_amdgcn_mfma_f32_16x16x32_bf16(af, b0, acc0, 0, 0, 0);
    short8 b1 = *(const short8*)&TB[(1 * 16 + lq) * 264 + kc * 32 + g * 8];
    acc1 = __builtin_amdgcn_mfma_f32_16x16x32_bf16(af, b1, acc1, 0, 0, 0);
    short8 b2 = *(const short8*)&TB[(2 * 16 + lq) * 264 + kc * 32 + g * 8];
    acc2 = __builtin_amdgcn_mfma_f32_16x16x32_bf16(af, b2, acc2, 0, 0, 0);
    short8 b3 = *(const short8*)&TB[(3 * 16 + lq) * 264 + kc * 32 + g * 8];
    acc3 = __builtin_amdgcn_mfma_f32_16x16x32_bf16(af, b3, acc3, 0, 0, 0);
  }

  if (p < 2) {
    unsigned short* dst = (p == 0 ? qo : ko);
    const float scl = (p == 0 ? 1.f : S2LOG);
    #pragma unroll
    for (int c = 0; c < 4; ++c) {
      const f32x4 ac = (c == 0 ? acc0 : c == 1 ? acc1 : c == 2 ? acc2 : acc3);
      #pragma unroll
      for (int r = 0; r < 4; ++r) {
        int n = rb * 64 + wave * 16 + g * 4 + r;
        dst[(size_t)n * D_ + c * 16 + lq] = f2bf(ac[r] * scl);
      }
    }
  } else {
    int bb = (rb * 64) >> 12;
    #pragma unroll
    for (int c = 0; c < 4; ++c) {
      const f32x4 ac = (c == 0 ? acc0 : c == 1 ? acc1 : c == 2 ? acc2 : acc3);
      #pragma unroll
      for (int r = 0; r < 4; ++r) {
        int d = wave * 16 + g * 4 + r;
        int n = (rb * 64 + c * 16 + lq) & (N_ - 1);
        vto[((size_t)bb * D_ + d) * N_ + KSWAP(n)] = f2bf(ac[r]);
      }
    }
    // fused vmean partial: acc_c[r] = V[d = wave*16+g*4+r][n = rb*64+c*16+lq];
    // sum over c + 16-lane lq reduce covers the block's 64 keys per d.
    #pragma unroll
    for (int r = 0; r < 4; ++r) {
      float s = acc0[r] + acc1[r] + acc2[r] + acc3[r];
      s += __shfl_xor(s, 1, 64);
      s += __shfl_xor(s, 2, 64);
      s += __shfl_xor(s, 4, 64);
      s += __shfl_xor(s, 8, 64);
      if (lq == 0)
        atomicAdd(&vmean[bb * D_ + wave * 16 + g * 4 + r], s * (1.f / N_));
    }
  }
}

// ---------------------------------------------------------------------------
// Flash attention, KV-split (champion R17 structure, unchanged): 32x32x16
// MFMA, 4 waves x 32 q, reg-staged double-buffered LDS (128B rows +
// chunk^(row&7) swizzle), widened phases (both 32-key blocks' QK^T
// back-to-back, 32-wide exp/pack, 8-MFMA PV), in-register P with KSWAP'd
// vT, no-max exp2-direct softmax, plain-sum merge.
// ---------------------------------------------------------------------------
__global__ __launch_bounds__(256, 3) void attn17_kernel(
    const ushort_t* __restrict__ q, const ushort_t* __restrict__ kk,
    const ushort_t* __restrict__ vt, const float* __restrict__ biasf,
    float* __restrict__ op0, float* __restrict__ opws,
    float* __restrict__ lbuf, int nsplit)
{
  const int blk = blockIdx.x;
  const int xcd = blk & 7, half = xcd & 1;
  const int b = xcd >> 1;                       // batch pinned to XCD pair
  const int i = blk >> 3;
  const int qt = i & 31;                        // 32 q-tiles of 128
  const int sp = half * (nsplit >> 1) + (i >> 5);

  const int t = threadIdx.x;
  const int wave = t >> 6, lane = t & 63;
  const int l31 = lane & 31, hi = lane >> 5;

  const int TT = N_ / 64;
  const int tile_lo = (sp * TT) / nsplit;
  const int tile_hi = ((sp + 1) * TT) / nsplit;
  const int cnt = tile_hi - tile_lo;

  __align__(16) __shared__ ushort_t Kt[2][64 * 64];   // [key][d], chunk^(row&7)
  __align__(16) __shared__ ushort_t Vt[2][64 * 64];   // [d][key-perm], same swz

  const int qw = qt * 128 + wave * 32;          // wave's first q (within batch)
  const size_t qrow = (size_t)(b * N_ + qw + l31) * D_;
  short8 qr0 = *(const short8*)&q[qrow + 0  + 8 * hi];
  short8 qr1 = *(const short8*)&q[qrow + 16 + 8 * hi];
  short8 qr2 = *(const short8*)&q[qrow + 32 + 8 * hi];
  short8 qr3 = *(const short8*)&q[qrow + 48 + 8 * hi];

  const float* biasb = biasf + b * N_;
  const int swz = l31 & 7;

  float lsum = 0.f;
  f32x16 o0, o1;                                // O'[q=ROWPAT(r)+4hi][d=l31(+32)]
  #pragma unroll
  for (int r = 0; r < 16; ++r) { o0[r] = 0.f; o1[r] = 0.f; }

  // staging: 256 threads, 2 chunk-pairs each (rows r0 and r0+32)
  const int r0 = t >> 3, j0 = t & 7;
  const int r1 = 32 + r0;
  uint4 k0r, k1r, v0r, v1r;

  auto stage_load = [&](int tile) {
    const int jb = (tile_lo + tile) * 64;
    const ushort_t* kbase = kk + (size_t)(b * N_ + jb) * D_;
    k0r = *(const uint4*)&kbase[(size_t)r0 * D_ + j0 * 8];
    k1r = *(const uint4*)&kbase[(size_t)r1 * D_ + j0 * 8];
    const ushort_t* vbase = vt + (size_t)b * D_ * N_ + jb;
    v0r = *(const uint4*)&vbase[(size_t)r0 * N_ + j0 * 8];
    v1r = *(const uint4*)&vbase[(size_t)r1 * N_ + j0 * 8];
  };
  auto stage_write = [&](int bufi) {
    *(uint4*)&Kt[bufi][r0 * 64 + ((j0 ^ (r0 & 7)) * 8)] = k0r;
    *(uint4*)&Kt[bufi][r1 * 64 + ((j0 ^ (r1 & 7)) * 8)] = k1r;
    *(uint4*)&Vt[bufi][r0 * 64 + ((j0 ^ (r0 & 7)) * 8)] = v0r;
    *(uint4*)&Vt[bufi][r1 * 64 + ((j0 ^ (r1 & 7)) * 8)] = v1r;
  };

  stage_load(0);
  stage_write(0);
  __syncthreads();

  for (int it = 0; it < cnt; ++it) {
    const int bufi = it & 1;
    const int jb = (tile_lo + it) * 64;
    const bool more = (it + 1 < cnt);
    if (more) stage_load(it + 1);               // VMEM in flight across compute

    // ---- QK^T for BOTH 32-key blocks (2 independent 4-MFMA chains) ----
    f32x16 st0, st1;
    #pragma unroll
    for (int r = 0; r < 16; ++r) { st0[r] = 0.f; st1[r] = 0.f; }
    {
      const ushort_t* Kb0 = &Kt[bufi][(0 * 32 + l31) * 64];
      const ushort_t* Kb1 = &Kt[bufi][(1 * 32 + l31) * 64];
      short8 ka, kb_;
      ka  = *(const short8*)&Kb0[((0 + hi) ^ swz) * 8];
      kb_ = *(const short8*)&Kb1[((0 + hi) ^ swz) * 8];
      st0 = __builtin_amdgcn_mfma_f32_32x32x16_bf16(ka,  qr0, st0, 0, 0, 0);
      st1 = __builtin_amdgcn_mfma_f32_32x32x16_bf16(kb_, qr0, st1, 0, 0, 0);
      ka  = *(const short8*)&Kb0[((2 + hi) ^ swz) * 8];
      kb_ = *(const short8*)&Kb1[((2 + hi) ^ swz) * 8];
      st0 = __builtin_amdgcn_mfma_f32_32x32x16_bf16(ka,  qr1, st0, 0, 0, 0);
      st1 = __builtin_amdgcn_mfma_f32_32x32x16_bf16(kb_, qr1, st1, 0, 0, 0);
      ka  = *(const short8*)&Kb0[((4 + hi) ^ swz) * 8];
      kb_ = *(const short8*)&Kb1[((4 + hi) ^ swz) * 8];
      st0 = __builtin_amdgcn_mfma_f32_32x32x16_bf16(ka,  qr2, st0, 0, 0, 0);
      st1 = __builtin_amdgcn_mfma_f32_32x32x16_bf16(kb_, qr2, st1, 0, 0, 0);
      ka  = *(const short8*)&Kb0[((6 + hi) ^ swz) * 8];
      kb_ = *(const short8*)&Kb1[((6 + hi) ^ swz) * 8];
      st0 = __builtin_amdgcn_mfma_f32_32x32x16_bf16(ka,  qr3, st0, 0, 0, 0);
      st1 = __builtin_amdgcn_mfma_f32_32x32x16_bf16(kb_, qr3, st1, 0, 0, 0);
    }

    // ---- P = exp2(s + bias), 32-wide independent ----
    {
      const float* bj0 = &biasb[jb + 4 * hi];
      const float* bj1 = &biasb[jb + 32 + 4 * hi];
      float4 a0 = *(const float4*)&bj0[0];
      float4 a1 = *(const float4*)&bj0[8];
      float4 a2 = *(const float4*)&bj0[16];
      float4 a3 = *(const float4*)&bj0[24];
      float4 c0 = *(const float4*)&bj1[0];
      float4 c1 = *(const float4*)&bj1[8];
      float4 c2 = *(const float4*)&bj1[16];
      float4 c3 = *(const float4*)&bj1[24];
      st0[0]  = exp2_fast(st0[0]  + a0.x);  st1[0]  = exp2_fast(st1[0]  + c0.x);
      st0[1]  = exp2_fast(st0[1]  + a0.y);  st1[1]  = exp2_fast(st1[1]  + c0.y);
      st0[2]  = exp2_fast(st0[2]  + a0.z);  st1[2]  = exp2_fast(st1[2]  + c0.z);
      st0[3]  = exp2_fast(st0[3]  + a0.w);  st1[3]  = exp2_fast(st1[3]  + c0.w);
      st0[4]  = exp2_fast(st0[4]  + a1.x);  st1[4]  = exp2_fast(st1[4]  + c1.x);
      st0[5]  = exp2_fast(st0[5]  + a1.y);  st1[5]  = exp2_fast(st1[5]  + c1.y);
      st0[6]  = exp2_fast(st0[6]  + a1.z);  st1[6]  = exp2_fast(st1[6]  + c1.z);
      st0[7]  = exp2_fast(st0[7]  + a1.w);  st1[7]  = exp2_fast(st1[7]  + c1.w);
      st0[8]  = exp2_fast(st0[8]  + a2.x);  st1[8]  = exp2_fast(st1[8]  + c2.x);
      st0[9]  = exp2_fast(st0[9]  + a2.y);  st1[9]  = exp2_fast(st1[9]  + c2.y);
      st0[10] = exp2_fast(st0[10] + a2.z);  st1[10] = exp2_fast(st1[10] + c2.z);
      st0[11] = exp2_fast(st0[11] + a2.w);  st1[11] = exp2_fast(st1[11] + c2.w);
      st0[12] = exp2_fast(st0[12] + a3.x);  st1[12] = exp2_fast(st1[12] + c3.x);
      st0[13] = exp2_fast(st0[13] + a3.y);  st1[13] = exp2_fast(st1[13] + c3.y);
      st0[14] = exp2_fast(st0[14] + a3.z);  st1[14] = exp2_fast(st1[14] + c3.z);
      st0[15] = exp2_fast(st0[15] + a3.w);  st1[15] = exp2_fast(st1[15] + c3.w);
    }

    if (jb == (qw & ~63)) {                     // diagonal tile (wave-uniform)
      const int dloc = l31 - 4 * hi;
      const int qkb = (qw >> 5) & 1;            // which 32-block holds the diag
      #pragma unroll
      for (int r = 0; r < 16; ++r) {
        if (qkb == 0) st0[r] = (ROWPAT(r) == dloc) ? 0.f : st0[r];
        else          st1[r] = (ROWPAT(r) == dloc) ? 0.f : st1[r];
      }
    }

    // ---- lane-local l partial ----
    {
      float s0 = ((st0[0] + st0[1]) + (st0[2] + st0[3])) + ((st0[4] + st0[5]) + (st0[6] + st0[7]));
      float s1 = ((st0[8] + st0[9]) + (st0[10] + st0[11])) + ((st0[12] + st0[13]) + (st0[14] + st0[15]));
      float s2 = ((st1[0] + st1[1]) + (st1[2] + st1[3])) + ((st1[4] + st1[5]) + (st1[6] + st1[7]));
      float s3 = ((st1[8] + st1[9]) + (st1[10] + st1[11])) + ((st1[12] + st1[13]) + (st1[14] + st1[15]));
      lsum += (s0 + s1) + (s2 + s3);
    }

    // ---- pack P (key-permuted, natural reg order) ----
    union { unsigned u[4]; short8 s; } A0, A1, A2, A3;
    A0.u[0] = cvt_pk_bf16(st0[0],  st0[1]);
    A0.u[1] = cvt_pk_bf16(st0[2],  st0[3]);
    A0.u[2] = cvt_pk_bf16(st0[4],  st0[5]);
    A0.u[3] = cvt_pk_bf16(st0[6],  st0[7]);
    A1.u[0] = cvt_pk_bf16(st0[8],  st0[9]);
    A1.u[1] = cvt_pk_bf16(st0[10], st0[11]);
    A1.u[2] = cvt_pk_bf16(st0[12], st0[13]);
    A1.u[3] = cvt_pk_bf16(st0[14], st0[15]);
    A2.u[0] = cvt_pk_bf16(st1[0],  st1[1]);
    A2.u[1] = cvt_pk_bf16(st1[2],  st1[3]);
    A2.u[2] = cvt_pk_bf16(st1[4],  st1[5]);
    A2.u[3] = cvt_pk_bf16(st1[6],  st1[7]);
    A3.u[0] = cvt_pk_bf16(st1[8],  st1[9]);
    A3.u[1] = cvt_pk_bf16(st1[10], st1[11]);
    A3.u[2] = cvt_pk_bf16(st1[12], st1[13]);
    A3.u[3] = cvt_pk_bf16(st1[14], st1[15]);

    // ---- PV for both blocks (2 independent accumulator chains) ----
    {
      const ushort_t* Vb0 = &Vt[bufi][(0 * 32 + l31) * 64];
      const ushort_t* Vb1 = &Vt[bufi][(1 * 32 + l31) * 64];
      short8 va, vb;
      va = *(const short8*)&Vb0[((0 + hi) ^ swz) * 8];
      vb = *(const short8*)&Vb1[((0 + hi) ^ swz) * 8];
      o0 = __builtin_amdgcn_mfma_f32_32x32x16_bf16(A0.s, va, o0, 0, 0, 0);
      o1 = __builtin_amdgcn_mfma_f32_32x32x16_bf16(A0.s, vb, o1, 0, 0, 0);
      va = *(const short8*)&Vb0[((2 + hi) ^ swz) * 8];
      vb = *(const short8*)&Vb1[((2 + hi) ^ swz) * 8];
      o0 = __builtin_amdgcn_mfma_f32_32x32x16_bf16(A1.s, va, o0, 0, 0, 0);
      o1 = __builtin_amdgcn_mfma_f32_32x32x16_bf16(A1.s, vb, o1, 0, 0, 0);
      va = *(const short8*)&Vb0[((4 + hi) ^ swz) * 8];
      vb = *(const short8*)&Vb1[((4 + hi) ^ swz) * 8];
      o0 = __builtin_amdgcn_mfma_f32_32x32x16_bf16(A2.s, va, o0, 0, 0, 0);
      o1 = __builtin_amdgcn_mfma_f32_32x32x16_bf16(A2.s, vb, o1, 0, 0, 0);
      va = *(const short8*)&Vb0[((6 + hi) ^ swz) * 8];
      vb = *(const short8*)&Vb1[((6 + hi) ^ swz) * 8];
      o0 = __builtin_amdgcn_mfma_f32_32x32x16_bf16(A3.s, va, o0, 0, 0, 0);
      o1 = __builtin_amdgcn_mfma_f32_32x32x16_bf16(A3.s, vb, o1, 0, 0, 0);
    }

    if (more) stage_write(bufi ^ 1);            // vmcnt inserted by compiler
    __syncthreads();
  }

  // ---- epilogue: unnormalized O' + l ----
  float* obase = (sp == 0 ? op0 : opws + (size_t)(sp - 1) * (B_ * N_) * D_)
               + ((size_t)(b * N_) + qw) * D_ + l31;
  #pragma unroll
  for (int r = 0; r < 16; ++r) {
    obase[(size_t)(ROWPAT(r) + 4 * hi) * D_]      = o0[r];
    obase[(size_t)(ROWPAT(r) + 4 * hi) * D_ + 32] = o1[r];
  }
  float lt = lsum + __shfl_xor(lsum, 32, 64);
  if (lane < 32)
    lbuf[(size_t)sp * (B_ * N_) + b * N_ + qw + lane] = lt;
}

// ---------------------------------------------------------------------------
// Merge splits by PLAIN SUM (no max): out = sum_s O'_s / sum_s l_s.
// Dead q-rows get the reference's uniform mean over all V.
// ---------------------------------------------------------------------------
__global__ __launch_bounds__(256) void merge_kernel(
    const float* __restrict__ op0, const float* __restrict__ opws,
    const float* __restrict__ lbuf, const int* __restrict__ mask,
    const float* __restrict__ vmean, float* __restrict__ out, int nsplit)
{
  const int t = threadIdx.x;
  const int qrow = blockIdx.x * 16 + (t >> 4);
  const int d = (t & 15) * 4;
  const int b = qrow >> 12;

  if (!mask[qrow]) {
    *(float4*)&out[(size_t)qrow * D_ + d] = *(const float4*)&vmean[b * D_ + d];
    return;
  }

  float L = 0.f;
  float ax = 0.f, ay = 0.f, az = 0.f, aw = 0.f;
  for (int s = 0; s < nsplit; ++s) {
    L += lbuf[(size_t)s * (B_ * N_) + qrow];
    const float* ob = (s == 0) ? op0 : opws + (size_t)(s - 1) * (B_ * N_) * D_;
    float4 ov = *(const float4*)&ob[(size_t)qrow * D_ + d];
    ax += ov.x; ay += ov.y; az += ov.z; aw += ov.w;
  }
  const float inv = 1.f / L;
  float4 res; res.x = ax * inv; res.y = ay * inv; res.z = az * inv; res.w = aw * inv;
  *(float4*)&out[(size_t)qrow * D_ + d] = res;
}

// ---------------------------------------------------------------------------
extern "C" void kernel_launch(void* const* d_in, const int* in_sizes, int n_in,
                              void* d_out, int out_size, void* d_ws, size_t ws_size,
                              hipStream_t stream) {
  (void)in_sizes; (void)n_in; (void)out_size;
  const float* Qv = (const float*)d_in[0];
  const float* Kv = (const float*)d_in[1];
  const float* Vv = (const float*)d_in[2];
  const int* mask = (const int*)d_in[3];
  const float* Wq = (const float*)d_in[4];
  const float* Wk = (const float*)d_in[5];
  const float* Wv = (const float*)d_in[6];
  float* out = (float*)d_out;

  ushort_t* qb_ = (ushort_t*)d_ws;                         // [B*N][64] bf16
  ushort_t* kb_ = qb_ + (size_t)B_ * N_ * D_;              // [B*N][64] bf16 (pre-scaled)
  ushort_t* vtb = kb_ + (size_t)B_ * N_ * D_;              // [B][64][N] bf16 (key-swapped)
  float* biasf  = (float*)(vtb + (size_t)B_ * N_ * D_);    // [B*N] f32
  float* vmean  = biasf + (size_t)B_ * N_;                 // [B][64] f32 (atomic accum)
  float* lbuf   = vmean + (size_t)B_ * D_;                 // [6][B*N] f32 max
  float* opws   = lbuf + (size_t)6 * B_ * N_;              // (nsplit-1) x [B*N][64] f32
  const size_t fixed_bytes = (size_t)((char*)opws - (char*)d_ws);
  const size_t slice_bytes = (size_t)B_ * N_ * D_ * sizeof(float);

  int nsplit = 2;
  if      (ws_size >= fixed_bytes + 5 * slice_bytes) nsplit = 6;
  else if (ws_size >= fixed_bytes + 3 * slice_bytes) nsplit = 4;

  hipMemsetAsync(vmean, 0, (size_t)B_ * D_ * sizeof(float), stream);
  proj_kernel<<<dim3(256, 3), dim3(256), 0, stream>>>(
      Qv, Kv, Vv, Wq, Wk, Wv, mask, qb_, kb_, vtb, biasf, vmean);
  attn17_kernel<<<dim3(128 * nsplit), dim3(256), 0, stream>>>(
      qb_, kb_, vtb, biasf, out, opws, lbuf, nsplit);
  merge_kernel<<<dim3(B_ * N_ / 16), dim3(256), 0, stream>>>(
      out, opws, lbuf, mask, vmean, out, nsplit);
}

// Round 19
// 52.853 us; speedup vs baseline: 1.1298x; 1.1298x over previous
//
#include <hip/hip_runtime.h>

typedef __attribute__((ext_vector_type(8))) short short8;
typedef __attribute__((ext_vector_type(4))) float f32x4;
typedef __attribute__((ext_vector_type(16))) float f32x16;
typedef unsigned short ushort_t;

#define B_ 4
#define N_ 4096
#define E_ 256
#define D_ 64
#define S2LOG 0.1803368801111204f   // (1/sqrt(64)) * log2(e), folded into K' at proj
#define BIGNEG (-1e30f)
#define ROWPAT(r) ((((r)&3)) + 8*((r)>>2))
// vT key-position permutation: swap bits 2<->3 (involution)
#define KSWAP(n) (((n) & ~12) | (((n) & 4) << 1) | (((n) & 8) >> 1))

static __device__ __forceinline__ unsigned short f2bf(float f) {
  union { float f; unsigned int u; } v; v.f = f;
  return (unsigned short)((v.u + 0x7fffu + ((v.u >> 16) & 1u)) >> 16);  // RNE
}
static __device__ __forceinline__ float bf2f(unsigned short h) {
  union { unsigned u; float f; } c; c.u = ((unsigned)h) << 16; return c.f;
}
static __device__ __forceinline__ float exp2_fast(float x) {
  float r; asm("v_exp_f32 %0, %1" : "=v"(r) : "v"(x)); return r;
}
static __device__ __forceinline__ unsigned cvt_pk_bf16(float lo, float hi) {
  unsigned r; asm("v_cvt_pk_bf16_f32 %0, %1, %2" : "=v"(r) : "v"(lo), "v"(hi));
  return r;
}

// ---------------------------------------------------------------------------
// Projection. p=0: q [B*N][64] (+ mask->bias f32); p=1: k' = S2LOG*k [B*N][64];
// p=2: vT [B][64][N] with key index bit2<->3 swapped (PV A-frag match).
// ---------------------------------------------------------------------------
__global__ __launch_bounds__(256) void proj_kernel(
    const float* __restrict__ Qv, const float* __restrict__ Kv,
    const float* __restrict__ Vv, const float* __restrict__ Wq,
    const float* __restrict__ Wk, const float* __restrict__ Wv,
    const int* __restrict__ mask,
    unsigned short* __restrict__ qo, unsigned short* __restrict__ ko,
    unsigned short* __restrict__ vto, float* __restrict__ biasf)
{
  const int p  = blockIdx.y;
  const int rb = blockIdx.x;
  const int t  = threadIdx.x;

  __align__(16) __shared__ unsigned short Xl[64 * 264];
  __align__(16) __shared__ unsigned short Wl[64 * 264];

  const float* xsrc = (p == 0 ? Qv : (p == 1 ? Kv : Vv)) + (size_t)rb * 64 * E_;
  const float* wsrc = (p == 0 ? Wq : (p == 1 ? Wk : Wv));

  if (p == 0 && t < 64) biasf[rb * 64 + t] = mask[rb * 64 + t] ? 0.f : BIGNEG;

  #pragma unroll
  for (int it = 0; it < 8; ++it) {
    int idx = it * 2048 + t * 8;
    int row = idx >> 8, col = idx & 255;
    float4 a0 = *(const float4*)(xsrc + idx);
    float4 a1 = *(const float4*)(xsrc + idx + 4);
    uint4 wx;
    wx.x = (unsigned)f2bf(a0.x) | ((unsigned)f2bf(a0.y) << 16);
    wx.y = (unsigned)f2bf(a0.z) | ((unsigned)f2bf(a0.w) << 16);
    wx.z = (unsigned)f2bf(a1.x) | ((unsigned)f2bf(a1.y) << 16);
    wx.w = (unsigned)f2bf(a1.z) | ((unsigned)f2bf(a1.w) << 16);
    *(uint4*)&Xl[row * 264 + col] = wx;
    float4 b0 = *(const float4*)(wsrc + idx);
    float4 b1 = *(const float4*)(wsrc + idx + 4);
    uint4 ww;
    ww.x = (unsigned)f2bf(b0.x) | ((unsigned)f2bf(b0.y) << 16);
    ww.y = (unsigned)f2bf(b0.z) | ((unsigned)f2bf(b0.w) << 16);
    ww.z = (unsigned)f2bf(b1.x) | ((unsigned)f2bf(b1.y) << 16);
    ww.w = (unsigned)f2bf(b1.z) | ((unsigned)f2bf(b1.w) << 16);
    *(uint4*)&Wl[row * 264 + col] = ww;
  }
  __syncthreads();

  const int wave = t >> 6, lane = t & 63, g = lane >> 4, lq = lane & 15;
  const unsigned short* TA = (p == 2) ? Wl : Xl;
  const unsigned short* TB = (p == 2) ? Xl : Wl;

  f32x4 acc0 = {0.f,0.f,0.f,0.f}, acc1 = acc0, acc2 = acc0, acc3 = acc0;
  #pragma unroll
  for (int kc = 0; kc < 8; ++kc) {
    short8 af = *(const short8*)&TA[(wave * 16 + lq) * 264 + kc * 32 + g * 8];
    short8 b0 = *(const short8*)&TB[(0 * 16 + lq) * 264 + kc * 32 + g * 8];
    acc0 = __builtin_amdgcn_mfma_f32_16x16x32_bf16(af, b0, acc0, 0, 0, 0);
    short8 b1 = *(const short8*)&TB[(1 * 16 + lq) * 264 + kc * 32 + g * 8];
    acc1 = __builtin_amdgcn_mfma_f32_16x16x32_bf16(af, b1, acc1, 0, 0, 0);
    short8 b2 = *(const short8*)&TB[(2 * 16 + lq) * 264 + kc * 32 + g * 8];
    acc2 = __builtin_amdgcn_mfma_f32_16x16x32_bf16(af, b2, acc2, 0, 0, 0);
    short8 b3 = *(const short8*)&TB[(3 * 16 + lq) * 264 + kc * 32 + g * 8];
    acc3 = __builtin_amdgcn_mfma_f32_16x16x32_bf16(af, b3, acc3, 0, 0, 0);
  }

  if (p < 2) {
    unsigned short* dst = (p == 0 ? qo : ko);
    const float scl = (p == 0 ? 1.f : S2LOG);
    #pragma unroll
    for (int c = 0; c < 4; ++c) {
      const f32x4 ac = (c == 0 ? acc0 : c == 1 ? acc1 : c == 2 ? acc2 : acc3);
      #pragma unroll
      for (int r = 0; r < 4; ++r) {
        int n = rb * 64 + wave * 16 + g * 4 + r;
        dst[(size_t)n * D_ + c * 16 + lq] = f2bf(ac[r] * scl);
      }
    }
  } else {
    int bb = (rb * 64) >> 12;
    #pragma unroll
    for (int c = 0; c < 4; ++c) {
      const f32x4 ac = (c == 0 ? acc0 : c == 1 ? acc1 : c == 2 ? acc2 : acc3);
      #pragma unroll
      for (int r = 0; r < 4; ++r) {
        int d = wave * 16 + g * 4 + r;
        int n = (rb * 64 + c * 16 + lq) & (N_ - 1);
        vto[((size_t)bb * D_ + d) * N_ + KSWAP(n)] = f2bf(ac[r]);
      }
    }
  }
}

// ---------------------------------------------------------------------------
// vmean[b][d] = (1/N) sum_n v[b][n][d]  (permutation-invariant sum).
// ---------------------------------------------------------------------------
__global__ __launch_bounds__(256) void vmean_kernel(
    const ushort_t* __restrict__ vt, float* __restrict__ vmean)
{
  const int t = threadIdx.x, wave = t >> 6, lane = t & 63;
  const int idx = blockIdx.x * 4 + wave;
  const ushort_t* row = vt + (size_t)idx * N_;
  float s = 0.f;
  #pragma unroll
  for (int i = 0; i < 8; ++i) {
    short8 v = *(const short8*)&row[(i * 64 + lane) * 8];
    #pragma unroll
    for (int j = 0; j < 8; ++j) s += bf2f((unsigned short)v[j]);
  }
  #pragma unroll
  for (int off = 1; off < 64; off <<= 1) s += __shfl_xor(s, off, 64);
  if (lane == 0) vmean[idx] = s * (1.f / N_);
}

// ---------------------------------------------------------------------------
// Flash attention, KV-split (champion R17 structure): 32x32x16 MFMA, 4 waves
// x 32 q, reg-staged double-buffered LDS (128B rows + chunk^(row&7) swizzle),
// widened phases (both 32-key blocks' QK^T back-to-back = 2 independent
// 4-MFMA chains, 32-wide exp/pack, 8-MFMA PV with 2 chains), in-register P
// with KSWAP'd vT, no-max exp2-direct softmax, plain-sum merge.
// ---------------------------------------------------------------------------
__global__ __launch_bounds__(256, 3) void attn17_kernel(
    const ushort_t* __restrict__ q, const ushort_t* __restrict__ kk,
    const ushort_t* __restrict__ vt, const float* __restrict__ biasf,
    float* __restrict__ op0, float* __restrict__ opws,
    float* __restrict__ lbuf, int nsplit)
{
  const int blk = blockIdx.x;
  const int xcd = blk & 7, half = xcd & 1;
  const int b = xcd >> 1;                       // batch pinned to XCD pair
  const int i = blk >> 3;
  const int qt = i & 31;                        // 32 q-tiles of 128
  const int sp = half * (nsplit >> 1) + (i >> 5);

  const int t = threadIdx.x;
  const int wave = t >> 6, lane = t & 63;
  const int l31 = lane & 31, hi = lane >> 5;

  const int TT = N_ / 64;
  const int tile_lo = (sp * TT) / nsplit;
  const int tile_hi = ((sp + 1) * TT) / nsplit;
  const int cnt = tile_hi - tile_lo;

  __align__(16) __shared__ ushort_t Kt[2][64 * 64];   // [key][d], chunk^(row&7)
  __align__(16) __shared__ ushort_t Vt[2][64 * 64];   // [d][key-perm], same swz

  const int qw = qt * 128 + wave * 32;          // wave's first q (within batch)
  const size_t qrow = (size_t)(b * N_ + qw + l31) * D_;
  short8 qr0 = *(const short8*)&q[qrow + 0  + 8 * hi];
  short8 qr1 = *(const short8*)&q[qrow + 16 + 8 * hi];
  short8 qr2 = *(const short8*)&q[qrow + 32 + 8 * hi];
  short8 qr3 = *(const short8*)&q[qrow + 48 + 8 * hi];

  const float* biasb = biasf + b * N_;
  const int swz = l31 & 7;

  float lsum = 0.f;
  f32x16 o0, o1;                                // O'[q=ROWPAT(r)+4hi][d=l31(+32)]
  #pragma unroll
  for (int r = 0; r < 16; ++r) { o0[r] = 0.f; o1[r] = 0.f; }

  // staging: 256 threads, 2 chunk-pairs each (rows r0 and r0+32)
  const int r0 = t >> 3, j0 = t & 7;
  const int r1 = 32 + r0;
  uint4 k0r, k1r, v0r, v1r;

  auto stage_load = [&](int tile) {
    const int jb = (tile_lo + tile) * 64;
    const ushort_t* kbase = kk + (size_t)(b * N_ + jb) * D_;
    k0r = *(const uint4*)&kbase[(size_t)r0 * D_ + j0 * 8];
    k1r = *(const uint4*)&kbase[(size_t)r1 * D_ + j0 * 8];
    const ushort_t* vbase = vt + (size_t)b * D_ * N_ + jb;
    v0r = *(const uint4*)&vbase[(size_t)r0 * N_ + j0 * 8];
    v1r = *(const uint4*)&vbase[(size_t)r1 * N_ + j0 * 8];
  };
  auto stage_write = [&](int bufi) {
    *(uint4*)&Kt[bufi][r0 * 64 + ((j0 ^ (r0 & 7)) * 8)] = k0r;
    *(uint4*)&Kt[bufi][r1 * 64 + ((j0 ^ (r1 & 7)) * 8)] = k1r;
    *(uint4*)&Vt[bufi][r0 * 64 + ((j0 ^ (r0 & 7)) * 8)] = v0r;
    *(uint4*)&Vt[bufi][r1 * 64 + ((j0 ^ (r1 & 7)) * 8)] = v1r;
  };

  stage_load(0);
  stage_write(0);
  __syncthreads();

  for (int it = 0; it < cnt; ++it) {
    const int bufi = it & 1;
    const int jb = (tile_lo + it) * 64;
    const bool more = (it + 1 < cnt);
    if (more) stage_load(it + 1);               // VMEM in flight across compute

    // ---- QK^T for BOTH 32-key blocks (2 independent 4-MFMA chains) ----
    f32x16 st0, st1;
    #pragma unroll
    for (int r = 0; r < 16; ++r) { st0[r] = 0.f; st1[r] = 0.f; }
    {
      const ushort_t* Kb0 = &Kt[bufi][(0 * 32 + l31) * 64];
      const ushort_t* Kb1 = &Kt[bufi][(1 * 32 + l31) * 64];
      short8 ka, kb_;
      ka  = *(const short8*)&Kb0[((0 + hi) ^ swz) * 8];
      kb_ = *(const short8*)&Kb1[((0 + hi) ^ swz) * 8];
      st0 = __builtin_amdgcn_mfma_f32_32x32x16_bf16(ka,  qr0, st0, 0, 0, 0);
      st1 = __builtin_amdgcn_mfma_f32_32x32x16_bf16(kb_, qr0, st1, 0, 0, 0);
      ka  = *(const short8*)&Kb0[((2 + hi) ^ swz) * 8];
      kb_ = *(const short8*)&Kb1[((2 + hi) ^ swz) * 8];
      st0 = __builtin_amdgcn_mfma_f32_32x32x16_bf16(ka,  qr1, st0, 0, 0, 0);
      st1 = __builtin_amdgcn_mfma_f32_32x32x16_bf16(kb_, qr1, st1, 0, 0, 0);
      ka  = *(const short8*)&Kb0[((4 + hi) ^ swz) * 8];
      kb_ = *(const short8*)&Kb1[((4 + hi) ^ swz) * 8];
      st0 = __builtin_amdgcn_mfma_f32_32x32x16_bf16(ka,  qr2, st0, 0, 0, 0);
      st1 = __builtin_amdgcn_mfma_f32_32x32x16_bf16(kb_, qr2, st1, 0, 0, 0);
      ka  = *(const short8*)&Kb0[((6 + hi) ^ swz) * 8];
      kb_ = *(const short8*)&Kb1[((6 + hi) ^ swz) * 8];
      st0 = __builtin_amdgcn_mfma_f32_32x32x16_bf16(ka,  qr3, st0, 0, 0, 0);
      st1 = __builtin_amdgcn_mfma_f32_32x32x16_bf16(kb_, qr3, st1, 0, 0, 0);
    }

    // ---- P = exp2(s + bias), 32-wide independent ----
    {
      const float* bj0 = &biasb[jb + 4 * hi];
      const float* bj1 = &biasb[jb + 32 + 4 * hi];
      float4 a0 = *(const float4*)&bj0[0];
      float4 a1 = *(const float4*)&bj0[8];
      float4 a2 = *(const float4*)&bj0[16];
      float4 a3 = *(const float4*)&bj0[24];
      float4 c0 = *(const float4*)&bj1[0];
      float4 c1 = *(const float4*)&bj1[8];
      float4 c2 = *(const float4*)&bj1[16];
      float4 c3 = *(const float4*)&bj1[24];
      st0[0]  = exp2_fast(st0[0]  + a0.x);  st1[0]  = exp2_fast(st1[0]  + c0.x);
      st0[1]  = exp2_fast(st0[1]  + a0.y);  st1[1]  = exp2_fast(st1[1]  + c0.y);
      st0[2]  = exp2_fast(st0[2]  + a0.z);  st1[2]  = exp2_fast(st1[2]  + c0.z);
      st0[3]  = exp2_fast(st0[3]  + a0.w);  st1[3]  = exp2_fast(st1[3]  + c0.w);
      st0[4]  = exp2_fast(st0[4]  + a1.x);  st1[4]  = exp2_fast(st1[4]  + c1.x);
      st0[5]  = exp2_fast(st0[5]  + a1.y);  st1[5]  = exp2_fast(st1[5]  + c1.y);
      st0[6]  = exp2_fast(st0[6]  + a1.z);  st1[6]  = exp2_fast(st1[6]  + c1.z);
      st0[7]  = exp2_fast(st0[7]  + a1.w);  st1[7]  = exp2_fast(st1[7]  + c1.w);
      st0[8]  = exp2_fast(st0[8]  + a2.x);  st1[8]  = exp2_fast(st1[8]  + c2.x);
      st0[9]  = exp2_fast(st0[9]  + a2.y);  st1[9]  = exp2_fast(st1[9]  + c2.y);
      st0[10] = exp2_fast(st0[10] + a2.z);  st1[10] = exp2_fast(st1[10] + c2.z);
      st0[11] = exp2_fast(st0[11] + a2.w);  st1[11] = exp2_fast(st1[11] + c2.w);
      st0[12] = exp2_fast(st0[12] + a3.x);  st1[12] = exp2_fast(st1[12] + c3.x);
      st0[13] = exp2_fast(st0[13] + a3.y);  st1[13] = exp2_fast(st1[13] + c3.y);
      st0[14] = exp2_fast(st0[14] + a3.z);  st1[14] = exp2_fast(st1[14] + c3.z);
      st0[15] = exp2_fast(st0[15] + a3.w);  st1[15] = exp2_fast(st1[15] + c3.w);
    }

    if (jb == (qw & ~63)) {                     // diagonal tile (wave-uniform)
      const int dloc = l31 - 4 * hi;
      const int qkb = (qw >> 5) & 1;            // which 32-block holds the diag
      #pragma unroll
      for (int r = 0; r < 16; ++r) {
        if (qkb == 0) st0[r] = (ROWPAT(r) == dloc) ? 0.f : st0[r];
        else          st1[r] = (ROWPAT(r) == dloc) ? 0.f : st1[r];
      }
    }

    // ---- lane-local l partial ----
    {
      float s0 = ((st0[0] + st0[1]) + (st0[2] + st0[3])) + ((st0[4] + st0[5]) + (st0[6] + st0[7]));
      float s1 = ((st0[8] + st0[9]) + (st0[10] + st0[11])) + ((st0[12] + st0[13]) + (st0[14] + st0[15]));
      float s2 = ((st1[0] + st1[1]) + (st1[2] + st1[3])) + ((st1[4] + st1[5]) + (st1[6] + st1[7]));
      float s3 = ((st1[8] + st1[9]) + (st1[10] + st1[11])) + ((st1[12] + st1[13]) + (st1[14] + st1[15]));
      lsum += (s0 + s1) + (s2 + s3);
    }

    // ---- pack P (key-permuted, natural reg order) ----
    union { unsigned u[4]; short8 s; } A0, A1, A2, A3;
    A0.u[0] = cvt_pk_bf16(st0[0],  st0[1]);
    A0.u[1] = cvt_pk_bf16(st0[2],  st0[3]);
    A0.u[2] = cvt_pk_bf16(st0[4],  st0[5]);
    A0.u[3] = cvt_pk_bf16(st0[6],  st0[7]);
    A1.u[0] = cvt_pk_bf16(st0[8],  st0[9]);
    A1.u[1] = cvt_pk_bf16(st0[10], st0[11]);
    A1.u[2] = cvt_pk_bf16(st0[12], st0[13]);
    A1.u[3] = cvt_pk_bf16(st0[14], st0[15]);
    A2.u[0] = cvt_pk_bf16(st1[0],  st1[1]);
    A2.u[1] = cvt_pk_bf16(st1[2],  st1[3]);
    A2.u[2] = cvt_pk_bf16(st1[4],  st1[5]);
    A2.u[3] = cvt_pk_bf16(st1[6],  st1[7]);
    A3.u[0] = cvt_pk_bf16(st1[8],  st1[9]);
    A3.u[1] = cvt_pk_bf16(st1[10], st1[11]);
    A3.u[2] = cvt_pk_bf16(st1[12], st1[13]);
    A3.u[3] = cvt_pk_bf16(st1[14], st1[15]);

    // ---- PV for both blocks (2 independent accumulator chains) ----
    {
      const ushort_t* Vb0 = &Vt[bufi][(0 * 32 + l31) * 64];
      const ushort_t* Vb1 = &Vt[bufi][(1 * 32 + l31) * 64];
      short8 va, vb;
      va = *(const short8*)&Vb0[((0 + hi) ^ swz) * 8];
      vb = *(const short8*)&Vb1[((0 + hi) ^ swz) * 8];
      o0 = __builtin_amdgcn_mfma_f32_32x32x16_bf16(A0.s, va, o0, 0, 0, 0);
      o1 = __builtin_amdgcn_mfma_f32_32x32x16_bf16(A0.s, vb, o1, 0, 0, 0);
      va = *(const short8*)&Vb0[((2 + hi) ^ swz) * 8];
      vb = *(const short8*)&Vb1[((2 + hi) ^ swz) * 8];
      o0 = __builtin_amdgcn_mfma_f32_32x32x16_bf16(A1.s, va, o0, 0, 0, 0);
      o1 = __builtin_amdgcn_mfma_f32_32x32x16_bf16(A1.s, vb, o1, 0, 0, 0);
      va = *(const short8*)&Vb0[((4 + hi) ^ swz) * 8];
      vb = *(const short8*)&Vb1[((4 + hi) ^ swz) * 8];
      o0 = __builtin_amdgcn_mfma_f32_32x32x16_bf16(A2.s, va, o0, 0, 0, 0);
      o1 = __builtin_amdgcn_mfma_f32_32x32x16_bf16(A2.s, vb, o1, 0, 0, 0);
      va = *(const short8*)&Vb0[((6 + hi) ^ swz) * 8];
      vb = *(const short8*)&Vb1[((6 + hi) ^ swz) * 8];
      o0 = __builtin_amdgcn_mfma_f32_32x32x16_bf16(A3.s, va, o0, 0, 0, 0);
      o1 = __builtin_amdgcn_mfma_f32_32x32x16_bf16(A3.s, vb, o1, 0, 0, 0);
    }

    if (more) stage_write(bufi ^ 1);            // vmcnt inserted by compiler
    __syncthreads();
  }

  // ---- epilogue: unnormalized O' + l ----
  float* obase = (sp == 0 ? op0 : opws + (size_t)(sp - 1) * (B_ * N_) * D_)
               + ((size_t)(b * N_) + qw) * D_ + l31;
  #pragma unroll
  for (int r = 0; r < 16; ++r) {
    obase[(size_t)(ROWPAT(r) + 4 * hi) * D_]      = o0[r];
    obase[(size_t)(ROWPAT(r) + 4 * hi) * D_ + 32] = o1[r];
  }
  float lt = lsum + __shfl_xor(lsum, 32, 64);
  if (lane < 32)
    lbuf[(size_t)sp * (B_ * N_) + b * N_ + qw + lane] = lt;
}

// ---------------------------------------------------------------------------
// Merge splits by PLAIN SUM (no max): out = sum_s O'_s / sum_s l_s.
// Dead q-rows get the reference's uniform mean over all V.
// ---------------------------------------------------------------------------
__global__ __launch_bounds__(256) void merge_kernel(
    const float* __restrict__ op0, const float* __restrict__ opws,
    const float* __restrict__ lbuf, const int* __restrict__ mask,
    const float* __restrict__ vmean, float* __restrict__ out, int nsplit)
{
  const int t = threadIdx.x;
  const int qrow = blockIdx.x * 16 + (t >> 4);
  const int d = (t & 15) * 4;
  const int b = qrow >> 12;

  if (!mask[qrow]) {
    *(float4*)&out[(size_t)qrow * D_ + d] = *(const float4*)&vmean[b * D_ + d];
    return;
  }

  float L = 0.f;
  float ax = 0.f, ay = 0.f, az = 0.f, aw = 0.f;
  for (int s = 0; s < nsplit; ++s) {
    L += lbuf[(size_t)s * (B_ * N_) + qrow];
    const float* ob = (s == 0) ? op0 : opws + (size_t)(s - 1) * (B_ * N_) * D_;
    float4 ov = *(const float4*)&ob[(size_t)qrow * D_ + d];
    ax += ov.x; ay += ov.y; az += ov.z; aw += ov.w;
  }
  const float inv = 1.f / L;
  float4 res; res.x = ax * inv; res.y = ay * inv; res.z = az * inv; res.w = aw * inv;
  *(float4*)&out[(size_t)qrow * D_ + d] = res;
}

// ---------------------------------------------------------------------------
extern "C" void kernel_launch(void* const* d_in, const int* in_sizes, int n_in,
                              void* d_out, int out_size, void* d_ws, size_t ws_size,
                              hipStream_t stream) {
  (void)in_sizes; (void)n_in; (void)out_size;
  const float* Qv = (const float*)d_in[0];
  const float* Kv = (const float*)d_in[1];
  const float* Vv = (const float*)d_in[2];
  const int* mask = (const int*)d_in[3];
  const float* Wq = (const float*)d_in[4];
  const float* Wk = (const float*)d_in[5];
  const float* Wv = (const float*)d_in[6];
  float* out = (float*)d_out;

  ushort_t* qb_ = (ushort_t*)d_ws;                         // [B*N][64] bf16
  ushort_t* kb_ = qb_ + (size_t)B_ * N_ * D_;              // [B*N][64] bf16 (pre-scaled)
  ushort_t* vtb = kb_ + (size_t)B_ * N_ * D_;              // [B][64][N] bf16 (key-swapped)
  float* biasf  = (float*)(vtb + (size_t)B_ * N_ * D_);    // [B*N] f32
  float* vmean  = biasf + (size_t)B_ * N_;                 // [B][64] f32
  float* lbuf   = vmean + (size_t)B_ * D_;                 // [6][B*N] f32 max
  float* opws   = lbuf + (size_t)6 * B_ * N_;              // (nsplit-1) x [B*N][64] f32
  const size_t fixed_bytes = (size_t)((char*)opws - (char*)d_ws);
  const size_t slice_bytes = (size_t)B_ * N_ * D_ * sizeof(float);

  int nsplit = 2;
  if      (ws_size >= fixed_bytes + 5 * slice_bytes) nsplit = 6;
  else if (ws_size >= fixed_bytes + 3 * slice_bytes) nsplit = 4;

  proj_kernel<<<dim3(256, 3), dim3(256), 0, stream>>>(
      Qv, Kv, Vv, Wq, Wk, Wv, mask, qb_, kb_, vtb, biasf);
  vmean_kernel<<<dim3(64), dim3(256), 0, stream>>>(vtb, vmean);
  attn17_kernel<<<dim3(128 * nsplit), dim3(256), 0, stream>>>(
      qb_, kb_, vtb, biasf, out, opws, lbuf, nsplit);
  merge_kernel<<<dim3(B_ * N_ / 16), dim3(256), 0, stream>>>(
      out, opws, lbuf, mask, vmean, out, nsplit);
}